// Round 2
// baseline (263.295 us; speedup 1.0000x reference)
//
#include <hip/hip_runtime.h>
#include <stdint.h>

#define K_DIM 1024
#define N_DIM 1024
#define BM 128
#define BN 128
#define BK 64
#define NK (K_DIM / BK)  // 16

typedef __attribute__((ext_vector_type(4))) float f32x4;
typedef __attribute__((ext_vector_type(8))) short bf16x8;
typedef __attribute__((ext_vector_type(4))) uint32_t u32x4;

// round-half-up to bf16 and pack two: low 16 = a, high 16 = b
__device__ __forceinline__ uint32_t pack_bf16(float a, float b) {
  uint32_t ua = __builtin_bit_cast(uint32_t, a) + 0x8000u;
  uint32_t ub = __builtin_bit_cast(uint32_t, b) + 0x8000u;
  return __builtin_amdgcn_perm(ub, ua, 0x07060302u);
}

__device__ __forceinline__ f32x4 wbin4(f32x4 v, float kkv, float aav) {
  f32x4 r;
#pragma unroll
  for (int i = 0; i < 4; ++i) {
    float t = v[i] * kkv;
    t = fminf(fmaxf(t, -1.0f), 1.0f);
    r[i] = t * aav;
  }
  return r;
}

// 128x128 tile, 4 waves 2x2, each wave 64x64 = 4x4 frags. BK=64, 2 k-subtiles.
// LDS row = 64 bf16 = 32 u32 = 8 slots x 16B. Swizzle: phys_slot = slot ^ (row&7).
// Double-buffered, one barrier per K-step, loads for t+1 issued before MFMA of t.
__global__ __launch_bounds__(256, 2) void binlin_gemm(
    const float* __restrict__ x, const float* __restrict__ w,
    const float* __restrict__ bias, const float* __restrict__ kkp,
    const float* __restrict__ aap, float* __restrict__ out) {
  __shared__ uint32_t lds[2][(BM + BN) * 32];  // 2 x 32 KB = 64 KB

  const int tid = threadIdx.x;

  // bijective XCD swizzle: 8 N-blocks of each m-panel land on the same XCD L2
  const int per = gridDim.x >> 3;  // gridDim.x % 8 == 0 by construction
  const int logical = (blockIdx.x & 7) * per + (blockIdx.x >> 3);
  const int mIdx = logical >> 3;
  const int nIdx = logical & 7;
  const int row0 = mIdx * BM;
  const int col0 = nIdx * BN;

  const float kkv = kkp[0];
  const float aav = aap[0];

  // staging: thread t -> row r = t>>1, half h = t&1 (32 consecutive floats each)
  const int r = tid >> 1;
  const int h = tid & 1;
  const int sw = r & 7;
  const float* ga = x + (size_t)(row0 + r) * K_DIM + h * 32;
  const float* gb = w + (size_t)(col0 + r) * K_DIM + h * 32;
  const int wbase = r * 32;  // word offset of this row in the tile

  const int wid = tid >> 6;
  const int wr = wid >> 1;
  const int wc = wid & 1;
  const int lane = tid & 63;
  const int cl = lane & 15;  // fragment row/col within 16
  const int kg = lane >> 4;  // 16B k-slot within the 32-wide k-subtile

  f32x4 acc[4][4] = {};
  f32x4 ra[8], rb[8];

#define LOADT(kt)                                              \
  {                                                            \
    const f32x4* pa = (const f32x4*)(ga + (kt)*BK);            \
    const f32x4* pb = (const f32x4*)(gb + (kt)*BK);            \
    _Pragma("unroll") for (int i = 0; i < 8; ++i) {            \
      ra[i] = pa[i];                                           \
      rb[i] = pb[i];                                           \
    }                                                          \
  }

#define STORET(buf)                                                            \
  {                                                                            \
    uint32_t* LA = &lds[buf][0] + wbase;                                       \
    uint32_t* LB = &lds[buf][BM * 32] + wbase;                                 \
    _Pragma("unroll") for (int j = 0; j < 4; ++j) {                            \
      u32x4 pk = {pack_bf16(ra[2 * j][0], ra[2 * j][1]),                       \
                  pack_bf16(ra[2 * j][2], ra[2 * j][3]),                       \
                  pack_bf16(ra[2 * j + 1][0], ra[2 * j + 1][1]),               \
                  pack_bf16(ra[2 * j + 1][2], ra[2 * j + 1][3])};              \
      *(u32x4*)(LA + (((h * 4 + j) ^ sw) * 4)) = pk;                           \
    }                                                                          \
    _Pragma("unroll") for (int j = 0; j < 4; ++j) {                            \
      f32x4 b0 = wbin4(rb[2 * j], kkv, aav);                                   \
      f32x4 b1 = wbin4(rb[2 * j + 1], kkv, aav);                               \
      u32x4 pk = {pack_bf16(b0[0], b0[1]), pack_bf16(b0[2], b0[3]),            \
                  pack_bf16(b1[0], b1[1]), pack_bf16(b1[2], b1[3])};           \
      *(u32x4*)(LB + (((h * 4 + j) ^ sw) * 4)) = pk;                           \
    }                                                                          \
  }

#define COMPUTET(buf)                                                          \
  {                                                                            \
    const uint32_t* A = &lds[buf][0];                                          \
    const uint32_t* B = &lds[buf][BM * 32];                                    \
    _Pragma("unroll") for (int ks = 0; ks < 2; ++ks) {                         \
      bf16x8 af[4], bfr[4];                                                    \
      _Pragma("unroll") for (int m = 0; m < 4; ++m) {                          \
        int rr = wr * 64 + m * 16 + cl;                                        \
        af[m] = *(const bf16x8*)(A + rr * 32 + (((ks * 4 + kg) ^ (rr & 7)) * 4)); \
      }                                                                        \
      _Pragma("unroll") for (int n = 0; n < 4; ++n) {                          \
        int rr = wc * 64 + n * 16 + cl;                                        \
        bfr[n] = *(const bf16x8*)(B + rr * 32 + (((ks * 4 + kg) ^ (rr & 7)) * 4)); \
      }                                                                        \
      _Pragma("unroll") for (int m = 0; m < 4; ++m)                            \
          _Pragma("unroll") for (int n = 0; n < 4; ++n)                        \
              acc[m][n] = __builtin_amdgcn_mfma_f32_16x16x32_bf16(             \
                  af[m], bfr[n], acc[m][n], 0, 0, 0);                          \
    }                                                                          \
  }

  // prologue: stage tile 0
  LOADT(0);
  STORET(0);

  int cur = 0;
  for (int kt = 0; kt < NK - 1; ++kt) {
    LOADT(kt + 1);    // issue next-tile global loads (latency hides under MFMA)
    __syncthreads();  // buf[cur] writes visible; prior reads of buf[cur^1] done
    COMPUTET(cur);
    STORET(cur ^ 1);  // waits vmcnt internally; writes other buffer
    cur ^= 1;
  }
  __syncthreads();
  COMPUTET(cur);

  // epilogue: bias + fp32 store
#pragma unroll
  for (int n = 0; n < 4; ++n) {
    int col = col0 + wc * 64 + n * 16 + cl;
    float bv = bias[col];
#pragma unroll
    for (int m = 0; m < 4; ++m) {
      int rowb = row0 + wr * 64 + m * 16 + kg * 4;
#pragma unroll
      for (int i = 0; i < 4; ++i) {
        out[(size_t)(rowb + i) * N_DIM + col] = acc[m][n][i] + bv;
      }
    }
  }
#undef LOADT
#undef STORET
#undef COMPUTET
}

extern "C" void kernel_launch(void* const* d_in, const int* in_sizes, int n_in,
                              void* d_out, int out_size, void* d_ws, size_t ws_size,
                              hipStream_t stream) {
  const float* x = (const float*)d_in[0];
  const float* w = (const float*)d_in[1];
  const float* bias = (const float*)d_in[2];
  const float* kk = (const float*)d_in[3];
  const float* aa = (const float*)d_in[4];
  float* out = (float*)d_out;

  const int M = in_sizes[0] / K_DIM;         // 32768
  const int grid = (M / BM) * (N_DIM / BN);  // 2048, divisible by 8
  binlin_gemm<<<grid, 256, 0, stream>>>(x, w, bias, kk, aa, out);
}

// Round 3
// 252.011 us; speedup vs baseline: 1.0448x; 1.0448x over previous
//
#include <hip/hip_runtime.h>
#include <stdint.h>

#define K_DIM 1024
#define N_DIM 1024
#define BM 128
#define BN 128
#define BK 64
#define NK (K_DIM / BK)  // 16

typedef __attribute__((ext_vector_type(4))) float f32x4;
typedef __attribute__((ext_vector_type(8))) short bf16x8;
typedef __attribute__((ext_vector_type(4))) uint32_t u32x4;

// round-half-up to bf16, pack two: low 16 = a, high 16 = b
__device__ __forceinline__ uint32_t pack_bf16(float a, float b) {
  uint32_t ua = __builtin_bit_cast(uint32_t, a) + 0x8000u;
  uint32_t ub = __builtin_bit_cast(uint32_t, b) + 0x8000u;
  return __builtin_amdgcn_perm(ub, ua, 0x07060302u);
}

__device__ __forceinline__ float wbin1(float v, float kkv, float aav) {
  float t = v * kkv;
  t = fminf(fmaxf(t, -1.0f), 1.0f);
  return t * aav;
}

// ---------------- kernel 1: w_bin = bf16(aa*clamp(kk*w,-1,1)) into ws ------
__global__ __launch_bounds__(256) void wconv(const float* __restrict__ w,
                                             const float* __restrict__ kkp,
                                             const float* __restrict__ aap,
                                             uint32_t* __restrict__ wb) {
  const float kkv = kkp[0];
  const float aav = aap[0];
  const int g = blockIdx.x * 256 + threadIdx.x;  // 16 floats per thread
  const f32x4* src = (const f32x4*)(w + (size_t)g * 16);
  f32x4 v0 = src[0], v1 = src[1], v2 = src[2], v3 = src[3];
  uint32_t p[8];
#pragma unroll
  for (int i = 0; i < 4; ++i) {
    f32x4 v = i == 0 ? v0 : (i == 1 ? v1 : (i == 2 ? v2 : v3));
    p[2 * i] = pack_bf16(wbin1(v[0], kkv, aav), wbin1(v[1], kkv, aav));
    p[2 * i + 1] = pack_bf16(wbin1(v[2], kkv, aav), wbin1(v[3], kkv, aav));
  }
  u32x4* dst = (u32x4*)(wb + (size_t)g * 8);
  dst[0] = u32x4{p[0], p[1], p[2], p[3]};
  dst[1] = u32x4{p[4], p[5], p[6], p[7]};
}

// ---------------- kernel 2: GEMM -------------------------------------------
// 128x128 tile, 4 waves 2x2, each wave 64x64 = 4x4 frags of 16x16, BK=64.
// LDS: single-buffered A[128][64] + B[128][64] bf16 = 32 KB.
// Row = 32 u32 = 8 slots x 16B; phys_slot = slot ^ (row&7) (both sides).
// B staged via global_load_lds (linear dest, source pre-swizzled, m173).
// A reg-staged fp32->bf16, ping-pong reg sets, loads issued one tile ahead.
__global__ __launch_bounds__(256, 4) void binlin_gemm(
    const float* __restrict__ x, const uint32_t* __restrict__ wb,
    const float* __restrict__ bias, float* __restrict__ out) {
  __shared__ uint32_t lA[BM * 32];  // 16 KB
  __shared__ uint32_t lB[BN * 32];  // 16 KB

  const int tid = threadIdx.x;

  // bijective XCD swizzle (grid % 8 == 0): 8 N-blocks of an m-panel share L2
  const int per = gridDim.x >> 3;
  const int logical = (blockIdx.x & 7) * per + (blockIdx.x >> 3);
  const int mIdx = logical >> 3;
  const int nIdx = logical & 7;
  const int row0 = mIdx * BM;
  const int col0 = nIdx * BN;

  // ---- A staging: thread t -> row r = t>>1, half h = t&1 (32 floats) ----
  const int r = tid >> 1;
  const int h = tid & 1;
  const int sw = r & 7;
  const float* ga = x + (size_t)(row0 + r) * K_DIM + h * 32;
  uint32_t* lap = lA + r * 32;

  // ---- B staging via global_load_lds: 4 calls/wave, 8 rows per call ----
  const int wid = tid >> 6;
  const int lane = tid & 63;
  const int brow_in8 = lane >> 3;             // row within 8-row group
  const int bslot = (lane & 7) ^ brow_in8;    // pre-swizzled source slot
  // per-call c: local row = wid*32 + c*8 + brow_in8  (row&7 == brow_in8)
  const uint32_t* gb_base =
      wb + (size_t)(col0 + wid * 32 + brow_in8) * (K_DIM / 2) + bslot * 4;
  uint32_t* lbp = lB + (wid * 32) * 32;

  // ---- compute-side indices ----
  const int wr = wid >> 1;
  const int wc = wid & 1;
  const int cl = lane & 15;
  const int kg = lane >> 4;

  f32x4 acc[4][4] = {};
  f32x4 ra[8], rb[8];

#define LOADA(kt, R)                                           \
  {                                                            \
    const f32x4* pa = (const f32x4*)(ga + (kt)*BK);            \
    _Pragma("unroll") for (int i = 0; i < 8; ++i) R[i] = pa[i];\
  }

#define WRITEA(R)                                                         \
  {                                                                       \
    _Pragma("unroll") for (int j = 0; j < 4; ++j) {                       \
      u32x4 pk = {pack_bf16(R[2 * j][0], R[2 * j][1]),                    \
                  pack_bf16(R[2 * j][2], R[2 * j][3]),                    \
                  pack_bf16(R[2 * j + 1][0], R[2 * j + 1][1]),            \
                  pack_bf16(R[2 * j + 1][2], R[2 * j + 1][3])};           \
      *(u32x4*)(lap + (((h * 4 + j) ^ sw) * 4)) = pk;                     \
    }                                                                     \
  }

#define STAGEB(kt)                                                        \
  {                                                                       \
    _Pragma("unroll") for (int c = 0; c < 4; ++c) {                       \
      __builtin_amdgcn_global_load_lds(                                   \
          (const __attribute__((address_space(1))) uint32_t*)(            \
              gb_base + (size_t)(c * 8) * (K_DIM / 2) + (kt) * 32),       \
          (__attribute__((address_space(3))) uint32_t*)(lbp + c * 8 * 32),\
          16, 0, 0);                                                      \
    }                                                                     \
  }

#define COMPUTE()                                                              \
  {                                                                            \
    _Pragma("unroll") for (int ks = 0; ks < 2; ++ks) {                         \
      bf16x8 af[4], bfr[4];                                                    \
      _Pragma("unroll") for (int m = 0; m < 4; ++m) {                          \
        int rr = wr * 64 + m * 16 + cl;                                        \
        af[m] = *(const bf16x8*)(lA + rr * 32 + (((ks * 4 + kg) ^ (rr & 7)) * 4)); \
      }                                                                        \
      _Pragma("unroll") for (int n = 0; n < 4; ++n) {                          \
        int rr = wc * 64 + n * 16 + cl;                                        \
        bfr[n] = *(const bf16x8*)(lB + rr * 32 + (((ks * 4 + kg) ^ (rr & 7)) * 4)); \
      }                                                                        \
      _Pragma("unroll") for (int m = 0; m < 4; ++m)                            \
          _Pragma("unroll") for (int n = 0; n < 4; ++n)                        \
              acc[m][n] = __builtin_amdgcn_mfma_f32_16x16x32_bf16(             \
                  af[m], bfr[n], acc[m][n], 0, 0, 0);                          \
    }                                                                          \
  }

#define STEP(kt, RCUR, RNXT, DOLOAD)  \
  {                                   \
    __syncthreads();                  \
    if (DOLOAD) LOADA((kt) + 1, RNXT);\
    STAGEB(kt);                       \
    WRITEA(RCUR);                     \
    __syncthreads();                  \
    COMPUTE();                        \
  }

  LOADA(0, ra);
#pragma unroll
  for (int kt2 = 0; kt2 < NK; kt2 += 2) {
    STEP(kt2, ra, rb, 1);
    STEP(kt2 + 1, rb, ra, (kt2 + 2) < NK);
  }

  // epilogue: bias + fp32 store
#pragma unroll
  for (int n = 0; n < 4; ++n) {
    int col = col0 + wc * 64 + n * 16 + cl;
    float bv = bias[col];
#pragma unroll
    for (int m = 0; m < 4; ++m) {
      int rowb = row0 + wr * 64 + m * 16 + kg * 4;
#pragma unroll
      for (int i = 0; i < 4; ++i) {
        out[(size_t)(rowb + i) * N_DIM + col] = acc[m][n][i] + bv;
      }
    }
  }
#undef LOADA
#undef WRITEA
#undef STAGEB
#undef COMPUTE
#undef STEP
}

extern "C" void kernel_launch(void* const* d_in, const int* in_sizes, int n_in,
                              void* d_out, int out_size, void* d_ws, size_t ws_size,
                              hipStream_t stream) {
  const float* x = (const float*)d_in[0];
  const float* w = (const float*)d_in[1];
  const float* bias = (const float*)d_in[2];
  const float* kk = (const float*)d_in[3];
  const float* aa = (const float*)d_in[4];
  float* out = (float*)d_out;
  uint32_t* wb = (uint32_t*)d_ws;  // 2 MB bf16 w_bin

  // kernel 1: binarize+convert W (1M elems, 16/thread)
  wconv<<<(N_DIM * K_DIM) / (256 * 16), 256, 0, stream>>>(w, kk, aa, wb);

  const int M = in_sizes[0] / K_DIM;         // 32768
  const int grid = (M / BM) * (N_DIM / BN);  // 2048
  binlin_gemm<<<grid, 256, 0, stream>>>(x, wb, bias, out);
}

// Round 4
// 158.853 us; speedup vs baseline: 1.6575x; 1.5864x over previous
//
#include <hip/hip_runtime.h>
#include <stdint.h>

#define K_DIM 1024
#define N_DIM 1024
#define BM 256
#define BN 256
#define BK 64
#define NK (K_DIM / BK)  // 16

typedef __attribute__((ext_vector_type(4))) float f32x4;
typedef __attribute__((ext_vector_type(8))) short bf16x8;
typedef __attribute__((ext_vector_type(4))) uint32_t u32x4;

// round-half-up to bf16, pack two: low 16 = a, high 16 = b
__device__ __forceinline__ uint32_t pack_bf16(float a, float b) {
  uint32_t ua = __builtin_bit_cast(uint32_t, a) + 0x8000u;
  uint32_t ub = __builtin_bit_cast(uint32_t, b) + 0x8000u;
  return __builtin_amdgcn_perm(ub, ua, 0x07060302u);
}

__device__ __forceinline__ float wbin1(float v, float kkv, float aav) {
  float t = v * kkv;
  t = fminf(fmaxf(t, -1.0f), 1.0f);
  return t * aav;
}

// ---------------- kernel 1: w_bin = bf16(aa*clamp(kk*w,-1,1)) into ws ------
__global__ __launch_bounds__(256) void wconv(const float* __restrict__ w,
                                             const float* __restrict__ kkp,
                                             const float* __restrict__ aap,
                                             uint32_t* __restrict__ wb) {
  const float kkv = kkp[0];
  const float aav = aap[0];
  const int g = blockIdx.x * 256 + threadIdx.x;  // 16 floats per thread
  const f32x4* src = (const f32x4*)(w + (size_t)g * 16);
  f32x4 v0 = src[0], v1 = src[1], v2 = src[2], v3 = src[3];
  uint32_t p[8];
#pragma unroll
  for (int i = 0; i < 4; ++i) {
    f32x4 v = i == 0 ? v0 : (i == 1 ? v1 : (i == 2 ? v2 : v3));
    p[2 * i] = pack_bf16(wbin1(v[0], kkv, aav), wbin1(v[1], kkv, aav));
    p[2 * i + 1] = pack_bf16(wbin1(v[2], kkv, aav), wbin1(v[3], kkv, aav));
  }
  u32x4* dst = (u32x4*)(wb + (size_t)g * 8);
  dst[0] = u32x4{p[0], p[1], p[2], p[3]};
  dst[1] = u32x4{p[4], p[5], p[6], p[7]};
}

// ---------------- kernel 2: GEMM -------------------------------------------
// 256x256 tile, 512 threads = 8 waves (2 wave-rows x 4 wave-cols), BK=64.
// Each wave: 128x64 output = 8x4 frags of 16x16, acc[8][4] f32x4.
// LDS double-buffered: per buf A[256][64]bf16 (32KB) + B[256][64]bf16 (32KB),
// total 128KB. Row = 32 u32 = 8 slots x 16B; phys_slot = slot ^ (row&7).
// Pipeline (1 barrier/tile): issue loads(t+1) -> COMPUTE(t) -> write A(t+1)
// -> barrier. Latency of t+1 loads hides under 64 MFMAs of tile t.
__global__ __launch_bounds__(512, 2) void binlin_gemm(
    const float* __restrict__ x, const uint32_t* __restrict__ wb,
    const float* __restrict__ bias, float* __restrict__ out) {
  __shared__ uint32_t lds[2][(BM + BN) * 32];  // 128 KB

  const int tid = threadIdx.x;

  // bijective XCD swizzle (grid=512, 64/XCD): the 4 n-blocks sharing an
  // m-panel are consecutive logicals -> same XCD L2.
  const int per = gridDim.x >> 3;
  const int logical = (blockIdx.x & 7) * per + (blockIdx.x >> 3);
  const int mIdx = logical >> 2;  // N_DIM/BN = 4
  const int nIdx = logical & 3;
  const int row0 = mIdx * BM;
  const int col0 = nIdx * BN;

  // ---- A staging: thread t -> row r = t>>1 (0..255), half h = t&1 ----
  const int r = tid >> 1;
  const int h = tid & 1;
  const int sw = r & 7;
  const float* ga = x + (size_t)(row0 + r) * K_DIM + h * 32;
  const int aoff = r * 32;  // u32 offset of row r in A region

  // ---- B staging via global_load_lds: wave w8 covers rows [w8*32, w8*32+32)
  const int w8 = tid >> 6;
  const int lane = tid & 63;
  const int brow = lane >> 3;               // row within 8-row group
  const int bslot = (lane & 7) ^ brow;      // pre-swizzled source slot
  const uint32_t* gb_base =
      wb + (size_t)(col0 + w8 * 32 + brow) * (K_DIM / 2) + bslot * 4;
  const int boff = (w8 * 32) * 32;  // u32 offset of wave's rows in B region

  // ---- compute indices ----
  const int wr = w8 >> 2;   // 0..1
  const int wc = w8 & 3;    // 0..3
  const int cl = lane & 15;
  const int kg = lane >> 4;

  f32x4 acc[8][4] = {};
  f32x4 ra[8];

#define LOADA(kt)                                               \
  {                                                             \
    const f32x4* pa = (const f32x4*)(ga + (kt)*BK);             \
    _Pragma("unroll") for (int i = 0; i < 8; ++i) ra[i] = pa[i];\
  }

#define WRITEA(buf)                                                       \
  {                                                                       \
    uint32_t* lap = &lds[buf][0] + aoff;                                  \
    _Pragma("unroll") for (int j = 0; j < 4; ++j) {                       \
      u32x4 pk = {pack_bf16(ra[2 * j][0], ra[2 * j][1]),                  \
                  pack_bf16(ra[2 * j][2], ra[2 * j][3]),                  \
                  pack_bf16(ra[2 * j + 1][0], ra[2 * j + 1][1]),          \
                  pack_bf16(ra[2 * j + 1][2], ra[2 * j + 1][3])};         \
      *(u32x4*)(lap + (((h * 4 + j) ^ sw) * 4)) = pk;                     \
    }                                                                     \
  }

#define STAGEB(kt, buf)                                                   \
  {                                                                       \
    uint32_t* lbp = &lds[buf][BM * 32] + boff;                            \
    _Pragma("unroll") for (int c = 0; c < 4; ++c) {                       \
      __builtin_amdgcn_global_load_lds(                                   \
          (const __attribute__((address_space(1))) uint32_t*)(            \
              gb_base + (size_t)(c * 8) * (K_DIM / 2) + (kt) * 32),       \
          (__attribute__((address_space(3))) uint32_t*)(lbp + c * 8 * 32),\
          16, 0, 0);                                                      \
    }                                                                     \
  }

#define COMPUTE(buf)                                                           \
  {                                                                            \
    const uint32_t* A = &lds[buf][0];                                          \
    const uint32_t* B = &lds[buf][BM * 32];                                    \
    _Pragma("unroll") for (int ks = 0; ks < 2; ++ks) {                         \
      bf16x8 bfr[4];                                                           \
      _Pragma("unroll") for (int n = 0; n < 4; ++n) {                          \
        int rr = wc * 64 + n * 16 + cl;                                        \
        bfr[n] = *(const bf16x8*)(B + rr * 32 + (((ks * 4 + kg) ^ (rr & 7)) * 4)); \
      }                                                                        \
      _Pragma("unroll") for (int mh = 0; mh < 2; ++mh) {                       \
        bf16x8 af[4];                                                          \
        _Pragma("unroll") for (int m = 0; m < 4; ++m) {                        \
          int rr = wr * 128 + (mh * 4 + m) * 16 + cl;                          \
          af[m] = *(const bf16x8*)(A + rr * 32 + (((ks * 4 + kg) ^ (rr & 7)) * 4)); \
        }                                                                      \
        __builtin_amdgcn_s_setprio(1);                                         \
        _Pragma("unroll") for (int m = 0; m < 4; ++m)                          \
            _Pragma("unroll") for (int n = 0; n < 4; ++n)                      \
                acc[mh * 4 + m][n] = __builtin_amdgcn_mfma_f32_16x16x32_bf16(  \
                    af[m], bfr[n], acc[mh * 4 + m][n], 0, 0, 0);               \
        __builtin_amdgcn_s_setprio(0);                                         \
      }                                                                        \
    }                                                                          \
  }

  // prologue: stage tile 0 into buf 0
  LOADA(0);
  STAGEB(0, 0);
  WRITEA(0);        // compiler inserts counted vmcnt for ra
  __syncthreads();  // drains B DMA (vmcnt) + A ds_writes (lgkm)

#pragma unroll 2
  for (int kt = 0; kt < NK; ++kt) {
    const int cur = kt & 1;
    if (kt < NK - 1) {
      LOADA(kt + 1);          // issue next A (regs)
      STAGEB(kt + 1, cur ^ 1);  // issue next B (DMA to other buffer)
    }
    COMPUTE(cur);             // ~64 MFMA/wave covers the load latency
    if (kt < NK - 1) WRITEA(cur ^ 1);  // counted vmcnt wait, convert, ds_write
    __syncthreads();          // one barrier per tile
  }

  // epilogue: bias + fp32 store
#pragma unroll
  for (int n = 0; n < 4; ++n) {
    int col = col0 + wc * 64 + n * 16 + cl;
    float bv = bias[col];
#pragma unroll
    for (int m = 0; m < 8; ++m) {
      int rowb = row0 + wr * 128 + m * 16 + kg * 4;
#pragma unroll
      for (int i = 0; i < 4; ++i) {
        out[(size_t)(rowb + i) * N_DIM + col] = acc[m][n][i] + bv;
      }
    }
  }
#undef LOADA
#undef WRITEA
#undef STAGEB
#undef COMPUTE
}

extern "C" void kernel_launch(void* const* d_in, const int* in_sizes, int n_in,
                              void* d_out, int out_size, void* d_ws, size_t ws_size,
                              hipStream_t stream) {
  const float* x = (const float*)d_in[0];
  const float* w = (const float*)d_in[1];
  const float* bias = (const float*)d_in[2];
  const float* kk = (const float*)d_in[3];
  const float* aa = (const float*)d_in[4];
  float* out = (float*)d_out;
  uint32_t* wb = (uint32_t*)d_ws;  // 2 MB bf16 w_bin

  wconv<<<(N_DIM * K_DIM) / (256 * 16), 256, 0, stream>>>(w, kk, aa, wb);

  const int M = in_sizes[0] / K_DIM;         // 32768
  const int grid = (M / BM) * (N_DIM / BN);  // 128 * 4 = 512
  binlin_gemm<<<grid, 512, 0, stream>>>(x, wb, bias, out);
}